// Round 10
// baseline (274.941 us; speedup 1.0000x reference)
//
#include <hip/hip_runtime.h>
#include <hip/hip_bf16.h>
#include <stdint.h>

#define P_B 4096
#define P_N 16384
#define P_F 768
#define P_E 512
#define NKT_F 24   // 768/32 k-tiles
#define NKT_E 16   // 512/32 k-tiles
#define CPAD 776   // convert LDS row pad (bf16 elems)
#define EPAD 136   // embed epilogue LDS row pad

typedef __attribute__((ext_vector_type(8))) __bf16 bf16x8;
typedef __attribute__((ext_vector_type(4))) float f32x4;

__device__ __forceinline__ unsigned short bfbits(float x) {
    __bf16 h = (__bf16)x;
    union { __bf16 h; unsigned short u; } cv;
    cv.h = h;
    return cv.u;
}
__device__ __forceinline__ float bf2f(unsigned short u) {
    union { float f; unsigned int i; } cv;
    cv.i = ((unsigned int)u) << 16;
    return cv.f;
}

// Fragment-packed layout: element (r,k) -> (((r>>4)*NKT + (k>>5))*64 +
// ((k>>3)&3)*16 + (r&15))*8 + (k&7). One wave fragment = contiguous 1KB.

// ---------------------------------------------------------------------------
// Convert+pack (+ zero-init of norm2/echo): fp32 row-major -> bf16
// fragment-packed via LDS transpose. Blocks 0..255 = X, 256..1279 = D,
// 1280..1311 = gw.
// ---------------------------------------------------------------------------
__global__ __launch_bounds__(256) void convert_pack_kernel(
    const float* __restrict__ X, const float* __restrict__ D,
    const float* __restrict__ gw,
    unsigned short* __restrict__ xdpk, unsigned short* __restrict__ gwpk,
    float* __restrict__ zbase)   // norm2(20480) | echo(4096)
{
    __shared__ unsigned short T[16 * CPAD];
    const int tid = threadIdx.x;
    const int rb = blockIdx.x;          // 0..1311

    if (rb < 97) {
        const int z = rb * 256 + tid;
        if (z < P_B + P_N + P_B) zbase[z] = 0.0f;
    }

    const float* src;
    unsigned short* dstbase;
    if (rb < 256)       { src = X  + (size_t)rb * 16 * P_F;          dstbase = xdpk + (size_t)rb * NKT_F * 512; }
    else if (rb < 1280) { src = D  + (size_t)(rb - 256) * 16 * P_F;  dstbase = xdpk + (size_t)rb * NKT_F * 512; }
    else                { src = gw + (size_t)(rb - 1280) * 16 * P_F; dstbase = gwpk + (size_t)(rb - 1280) * NKT_F * 512; }

#pragma unroll
    for (int it = 0; it < 12; ++it) {
        const int flat = it * 1024 + tid * 4;
        const int row = flat / P_F;
        const int col = flat - row * P_F;
        const float4 v = *(const float4*)(src + (size_t)row * P_F + col);
        unsigned short* t = &T[row * CPAD + col];
        t[0] = bfbits(v.x); t[1] = bfbits(v.y); t[2] = bfbits(v.z); t[3] = bfbits(v.w);
    }
    __syncthreads();

#pragma unroll
    for (int it = 0; it < 6; ++it) {
        const int m = it * 256 + tid;
        const int kt = m >> 6;          // 0..23
        const int lane = m & 63;
        const int r = lane & 15;
        const int k = kt * 32 + (lane >> 4) * 8;
        const uint4 frag = *(const uint4*)(&T[r * CPAD + k]);
        *(uint4*)(dstbase + (size_t)(kt * 64 + lane) * 8) = frag;
    }
}

// ---------------------------------------------------------------------------
// Embed v3: 64x128 tile, 1280 blocks (5/CU -> real latency-hiding queue).
// Wave w covers all 64 rows x cols [w*32, w*32+32). A-fragments shared by
// all 4 waves (L1 broadcast), barrier-free K-loop on packed fragments.
// acc = 32 regs -> ~76 VGPR, launch_bounds(256,4) safe.
// ---------------------------------------------------------------------------
__global__ __launch_bounds__(256, 4) void embed_pk_kernel(
    const unsigned short* __restrict__ xdpk, const unsigned short* __restrict__ gwpk,
    const float* __restrict__ gb,
    unsigned short* __restrict__ embpk, float* __restrict__ norm2)
{
    __shared__ unsigned short Es[64 * EPAD];
    const int tid = threadIdx.x, lane = tid & 63, wave = tid >> 6;
    const int q = lane >> 4, c = lane & 15;
    const int bid = blockIdx.x;                 // 0..1279
    const int rowTile = bid >> 2;               // 0..319 (64 rows each)
    const int colTile = bid & 3;                // 0..3 (128 cols each)
    const int rbA0 = rowTile * 4;
    const int rbB0 = colTile * 8 + wave * 2;

    const unsigned short* pa[4];
    const unsigned short* pb[2];
#pragma unroll
    for (int i = 0; i < 4; i++)
        pa[i] = xdpk + ((size_t)(rbA0 + i) * NKT_F * 64 + lane) * 8;
#pragma unroll
    for (int j = 0; j < 2; j++)
        pb[j] = gwpk + ((size_t)(rbB0 + j) * NKT_F * 64 + lane) * 8;

    f32x4 acc[4][2];
    const f32x4 zero = {0.f, 0.f, 0.f, 0.f};
#pragma unroll
    for (int i = 0; i < 4; i++)
#pragma unroll
        for (int j = 0; j < 2; j++) acc[i][j] = zero;

#pragma unroll
    for (int kt = 0; kt < NKT_F; ++kt) {
        bf16x8 af[4], bfr[2];
#pragma unroll
        for (int i = 0; i < 4; i++) af[i] = *(const bf16x8*)(pa[i] + (size_t)kt * 512);
#pragma unroll
        for (int j = 0; j < 2; j++) bfr[j] = *(const bf16x8*)(pb[j] + (size_t)kt * 512);
#pragma unroll
        for (int i = 0; i < 4; i++)
#pragma unroll
            for (int j = 0; j < 2; j++)
                acc[i][j] = __builtin_amdgcn_mfma_f32_16x16x32_bf16(af[i], bfr[j], acc[i][j], 0, 0, 0);
    }

    // epilogue: bias, ssq, LDS stash, coalesced packed stores
    float ss[4][4];
#pragma unroll
    for (int i = 0; i < 4; i++)
#pragma unroll
        for (int r = 0; r < 4; r++) ss[i][r] = 0.f;
#pragma unroll
    for (int j = 0; j < 2; j++) {
        const int lcbase = wave * 32 + j * 16 + c;
        const float bias = gb[colTile * 128 + lcbase];
#pragma unroll
        for (int i = 0; i < 4; i++) {
#pragma unroll
            for (int r = 0; r < 4; r++) {
                const int lr = i * 16 + q * 4 + r;
                const float v = acc[i][j][r] + bias;
                const unsigned short hb = bfbits(v);
                Es[lr * EPAD + lcbase] = hb;
                const float vs = bf2f(hb);
                ss[i][r] = fmaf(vs, vs, ss[i][r]);
            }
        }
    }
#pragma unroll
    for (int i = 0; i < 4; i++)
#pragma unroll
        for (int r = 0; r < 4; r++) {
            float s = ss[i][r];
            s += __shfl_xor(s, 1);
            s += __shfl_xor(s, 2);
            s += __shfl_xor(s, 4);
            s += __shfl_xor(s, 8);
            ss[i][r] = s;
        }
    if (c == 0) {
#pragma unroll
        for (int i = 0; i < 4; i++)
#pragma unroll
            for (int r = 0; r < 4; r++) {
                const int rowg = rowTile * 64 + i * 16 + q * 4 + r;
                atomicAdd(&norm2[rowg], ss[i][r]);
            }
    }
    __syncthreads();

    // packed store: 4 rbl x 4 kte x 64 lanes x 16B = 1024 chunks, 4 iters
#pragma unroll
    for (int it = 0; it < 4; ++it) {
        const int m = it * 256 + tid;
        const int rbl = m >> 8;             // 0..3
        const int rest = m & 255;
        const int ktl = rest >> 6;          // 0..3
        const int lane2 = rest & 63;
        const int r2 = lane2 & 15;
        const int q2 = lane2 >> 4;
        const int lr = rbl * 16 + r2;
        const int lc = ktl * 32 + q2 * 8;
        const uint4 frag = *(const uint4*)(&Es[lr * EPAD + lc]);
        const size_t rb = (size_t)(rowTile * 4 + rbl);
        const size_t kte = (size_t)(colTile * 4 + ktl);
        *(uint4*)(embpk + ((rb * NKT_E + kte) * 64 + lane2) * 8) = frag;
    }
}

// ---------------------------------------------------------------------------
// Finalize: norm2[i] -> inv_norm^3 (X rows), inv_norm^3 * (2r-1) (D rows)
// ---------------------------------------------------------------------------
__global__ void finalize_kernel(float* __restrict__ nf, const float* __restrict__ r)
{
    const int i = blockIdx.x * 256 + threadIdx.x;
    if (i >= P_B + P_N) return;
    float nrm = sqrtf(nf[i]);
    nrm = fmaxf(nrm, 1e-12f);
    const float inv = 1.0f / nrm;
    float w = inv * inv * inv;
    if (i >= P_B) {
        const float rv = r[i - P_B];
        w *= (2.0f * rv - 1.0f);
    }
    nf[i] = w;
}

// ---------------------------------------------------------------------------
// Echo v7: r6 kernel (128x128, occupancy 2, VGPR 80 — proven no-spill) with
// XCD-pinned locality: xcd=bid&7 owns 16 ntiles (2MB B-slab L2-resident);
// ntile-fast within XCD so each A-tile (128KB) stays hot for 16 consecutive
// blocks. Per-XCD working set ~2.5MB < 4MB L2.
// ---------------------------------------------------------------------------
__global__ __launch_bounds__(256, 2) void echo_pk_kernel(
    const unsigned short* __restrict__ embpk, const float* __restrict__ fbuf,
    float* __restrict__ echo)
{
    const int tid = threadIdx.x, lane = tid & 63, wave = tid >> 6;
    const int q = lane >> 4, c = lane & 15;
    const int bid = blockIdx.x;          // 0..4095
    const int xcd = bid & 7;
    const int rem = bid >> 3;            // 0..511
    const int btile = rem >> 4;          // 0..31 (slow)
    const int ntile = (xcd << 4) | (rem & 15);   // 0..127, partitioned per XCD
    const int row0 = btile * 128;
    const int col0 = ntile * 128;
    const int rbA0 = btile * 8 + (wave >> 1) * 4;
    const int rbB0 = 256 + ntile * 8 + (wave & 1) * 4;   // De rows start at rb 256

    const unsigned short* pa[4];
    const unsigned short* pb[4];
#pragma unroll
    for (int i = 0; i < 4; i++)
        pa[i] = embpk + ((size_t)(rbA0 + i) * NKT_E * 64 + lane) * 8;
#pragma unroll
    for (int j = 0; j < 4; j++)
        pb[j] = embpk + ((size_t)(rbB0 + j) * NKT_E * 64 + lane) * 8;

    f32x4 acc[4][4];
    const f32x4 zero = {0.f, 0.f, 0.f, 0.f};
#pragma unroll
    for (int i = 0; i < 4; i++)
#pragma unroll
        for (int j = 0; j < 4; j++) acc[i][j] = zero;

#pragma unroll
    for (int kt = 0; kt < NKT_E; ++kt) {
        bf16x8 af[4], bfr[4];
#pragma unroll
        for (int i = 0; i < 4; i++) af[i] = *(const bf16x8*)(pa[i] + (size_t)kt * 512);
#pragma unroll
        for (int j = 0; j < 4; j++) bfr[j] = *(const bf16x8*)(pb[j] + (size_t)kt * 512);
#pragma unroll
        for (int i = 0; i < 4; i++)
#pragma unroll
            for (int j = 0; j < 4; j++)
                acc[i][j] = __builtin_amdgcn_mfma_f32_16x16x32_bf16(af[i], bfr[j], acc[i][j], 0, 0, 0);
    }

    // epilogue: cube, weight by (ind^3*r2), reduce over columns, atomicAdd rows
    const float* fX = fbuf;
    const float* fD = fbuf + P_B;
    float wc[4];
#pragma unroll
    for (int j = 0; j < 4; j++) wc[j] = fD[col0 + (wave & 1) * 64 + j * 16 + c];
    float p[4][4];
#pragma unroll
    for (int i = 0; i < 4; i++)
#pragma unroll
        for (int r = 0; r < 4; r++) p[i][r] = 0.f;
#pragma unroll
    for (int i = 0; i < 4; i++)
#pragma unroll
        for (int j = 0; j < 4; j++)
#pragma unroll
            for (int r = 0; r < 4; r++) {
                const float v = acc[i][j][r];
                const float v3 = v * v * v;
                p[i][r] = fmaf(v3, wc[j], p[i][r]);
            }
#pragma unroll
    for (int i = 0; i < 4; i++)
#pragma unroll
        for (int r = 0; r < 4; r++) {
            float s = p[i][r];
            s += __shfl_xor(s, 1);
            s += __shfl_xor(s, 2);
            s += __shfl_xor(s, 4);
            s += __shfl_xor(s, 8);
            p[i][r] = s;
        }
    if (c == 0) {
#pragma unroll
        for (int i = 0; i < 4; i++)
#pragma unroll
            for (int r = 0; r < 4; r++) {
                const int rowg = row0 + (wave >> 1) * 64 + i * 16 + q * 4 + r;
                atomicAdd(&echo[rowg], p[i][r] * fX[rowg]);
            }
    }
}

// ---------------------------------------------------------------------------
// Head: logits = echo*h_w + h_b ; preds = sigmoid(logits)
// ---------------------------------------------------------------------------
__global__ void head_kernel(const float* __restrict__ echo, const float* __restrict__ hw,
                            const float* __restrict__ hb, float* __restrict__ out)
{
    const int i = blockIdx.x * 256 + threadIdx.x;
    if (i >= P_B) return;
    const float logit = fmaf(echo[i], hw[0], hb[0]);
    out[i] = logit;
    out[P_B + i] = 1.0f / (1.0f + expf(-logit));
}

extern "C" void kernel_launch(void* const* d_in, const int* in_sizes, int n_in,
                              void* d_out, int out_size, void* d_ws, size_t ws_size,
                              hipStream_t stream)
{
    const float* X  = (const float*)d_in[0];
    const float* D  = (const float*)d_in[1];
    const float* r  = (const float*)d_in[2];
    const float* gw = (const float*)d_in[3];
    const float* gb = (const float*)d_in[4];
    const float* hw = (const float*)d_in[5];
    const float* hb = (const float*)d_in[6];
    float* out = (float*)d_out;

    char* ws = (char*)d_ws;
    const size_t xdpk_bytes  = (size_t)1280 * NKT_F * 64 * 8 * 2;   // 31,457,280
    const size_t gwpk_bytes  = (size_t)32 * NKT_F * 64 * 8 * 2;     //    786,432
    const size_t embpk_bytes = (size_t)1280 * NKT_E * 64 * 8 * 2;   // 20,971,520

    unsigned short* xdpk  = (unsigned short*)ws;
    unsigned short* gwpk  = (unsigned short*)(ws + xdpk_bytes);
    unsigned short* embpk = (unsigned short*)(ws + xdpk_bytes + gwpk_bytes);
    float* norm2 = (float*)((char*)embpk + embpk_bytes);
    float* echo = norm2 + (P_B + P_N);

    convert_pack_kernel<<<dim3(1312), 256, 0, stream>>>(X, D, gw, xdpk, gwpk, norm2);
    embed_pk_kernel<<<dim3(1280), 256, 0, stream>>>(xdpk, gwpk, gb, embpk, norm2);
    finalize_kernel<<<dim3((P_B + P_N + 255) / 256), 256, 0, stream>>>(norm2, r);
    echo_pk_kernel<<<dim3(4096), 256, 0, stream>>>(embpk, norm2, echo);
    head_kernel<<<dim3((P_B + 255) / 256), 256, 0, stream>>>(echo, hw, hb, out);
}

// Round 11
// 196.108 us; speedup vs baseline: 1.4020x; 1.4020x over previous
//
#include <hip/hip_runtime.h>
#include <hip/hip_bf16.h>
#include <hip/hip_fp8.h>
#include <stdint.h>

#define P_B 4096
#define P_N 16384
#define P_F 768
#define P_E 512
#define NKT_F 24   // 768/32 k-tiles (bf16 packing, embed operands)
#define NKTP_E 8   // 512/64 k-tile-pairs (fp8 packing, echo operands)
#define CPAD 776   // convert LDS row pad (bf16 elems)
#define EPAD 136   // embed epilogue LDS row pad (bf16 elems)

typedef __attribute__((ext_vector_type(8))) __bf16 bf16x8;
typedef __attribute__((ext_vector_type(4))) float f32x4;

__device__ __forceinline__ unsigned short bfbits(float x) {
    __bf16 h = (__bf16)x;
    union { __bf16 h; unsigned short u; } cv;
    cv.h = h;
    return cv.u;
}
__device__ __forceinline__ float bf2f(unsigned short u) {
    union { float f; unsigned int i; } cv;
    cv.i = ((unsigned int)u) << 16;
    return cv.f;
}
__device__ __forceinline__ unsigned char f8bits(float x) {
    __hip_fp8_e4m3 h(x);           // OCP e4m3 on gfx950
    return (unsigned char)h.__x;
}

// bf16 fragment-packed (embed operands): element (r,k) ->
//   (((r>>4)*NKT_F + (k>>5))*64 + ((k>>3)&3)*16 + (r&15))*8 + (k&7)
// fp8 fragment-packed (echo operands), K grouped by 64 (two K=32 MFMA frags
// per 16B lane chunk): element (r,k) -> byte
//   (((r>>4)*NKTP_E + (k>>6))*64 + (((k>>3)&3)*16 + (r&15)))*16
//     + ((k>>5)&1)*8 + (k&7)

// ---------------------------------------------------------------------------
// Convert+pack (+ zero-init of norm2/echo): fp32 row-major -> bf16
// fragment-packed via LDS transpose. Blocks 0..255 = X, 256..1279 = D,
// 1280..1311 = gw.  (r6-proven)
// ---------------------------------------------------------------------------
__global__ __launch_bounds__(256) void convert_pack_kernel(
    const float* __restrict__ X, const float* __restrict__ D,
    const float* __restrict__ gw,
    unsigned short* __restrict__ xdpk, unsigned short* __restrict__ gwpk,
    float* __restrict__ zbase)   // norm2(20480) | echo(4096)
{
    __shared__ unsigned short T[16 * CPAD];
    const int tid = threadIdx.x;
    const int rb = blockIdx.x;          // 0..1311

    if (rb < 97) {
        const int z = rb * 256 + tid;
        if (z < P_B + P_N + P_B) zbase[z] = 0.0f;
    }

    const float* src;
    unsigned short* dstbase;
    if (rb < 256)       { src = X  + (size_t)rb * 16 * P_F;          dstbase = xdpk + (size_t)rb * NKT_F * 512; }
    else if (rb < 1280) { src = D  + (size_t)(rb - 256) * 16 * P_F;  dstbase = xdpk + (size_t)rb * NKT_F * 512; }
    else                { src = gw + (size_t)(rb - 1280) * 16 * P_F; dstbase = gwpk + (size_t)(rb - 1280) * NKT_F * 512; }

#pragma unroll
    for (int it = 0; it < 12; ++it) {
        const int flat = it * 1024 + tid * 4;
        const int row = flat / P_F;
        const int col = flat - row * P_F;
        const float4 v = *(const float4*)(src + (size_t)row * P_F + col);
        unsigned short* t = &T[row * CPAD + col];
        t[0] = bfbits(v.x); t[1] = bfbits(v.y); t[2] = bfbits(v.z); t[3] = bfbits(v.w);
    }
    __syncthreads();

#pragma unroll
    for (int it = 0; it < 6; ++it) {
        const int m = it * 256 + tid;
        const int kt = m >> 6;          // 0..23
        const int lane = m & 63;
        const int r = lane & 15;
        const int k = kt * 32 + (lane >> 4) * 8;
        const uint4 frag = *(const uint4*)(&T[r * CPAD + k]);
        *(uint4*)(dstbase + (size_t)(kt * 64 + lane) * 8) = frag;
    }
}

// ---------------------------------------------------------------------------
// Embed (r6-proven structure): emb = xd·gw^T + gb, barrier-free bf16 K-loop.
// Epilogue: bf16 LDS stash -> fp8 e4m3 conversion at read-out -> coalesced
// 16B packed stores (fp8 echo-operand layout) + per-row sum-of-squares.
// ---------------------------------------------------------------------------
__global__ __launch_bounds__(256, 2) void embed_pk_kernel(
    const unsigned short* __restrict__ xdpk, const unsigned short* __restrict__ gwpk,
    const float* __restrict__ gb,
    unsigned char* __restrict__ embpk8, float* __restrict__ norm2)
{
    __shared__ unsigned short Es[128 * EPAD];
    const int tid = threadIdx.x, lane = tid & 63, wave = tid >> 6;
    const int q = lane >> 4, c = lane & 15;
    const int colTile = blockIdx.x;   // 0..3
    const int rowTile = blockIdx.y;   // 0..159
    const int rbA0 = rowTile * 8 + (wave >> 1) * 4;
    const int rbB0 = colTile * 8 + (wave & 1) * 4;

    const unsigned short* pa[4];
    const unsigned short* pb[4];
#pragma unroll
    for (int i = 0; i < 4; i++)
        pa[i] = xdpk + ((size_t)(rbA0 + i) * NKT_F * 64 + lane) * 8;
#pragma unroll
    for (int j = 0; j < 4; j++)
        pb[j] = gwpk + ((size_t)(rbB0 + j) * NKT_F * 64 + lane) * 8;

    f32x4 acc[4][4];
    const f32x4 zero = {0.f, 0.f, 0.f, 0.f};
#pragma unroll
    for (int i = 0; i < 4; i++)
#pragma unroll
        for (int j = 0; j < 4; j++) acc[i][j] = zero;

#pragma unroll
    for (int kt = 0; kt < NKT_F; ++kt) {
        bf16x8 af[4], bfr[4];
#pragma unroll
        for (int i = 0; i < 4; i++) af[i] = *(const bf16x8*)(pa[i] + (size_t)kt * 512);
#pragma unroll
        for (int j = 0; j < 4; j++) bfr[j] = *(const bf16x8*)(pb[j] + (size_t)kt * 512);
#pragma unroll
        for (int i = 0; i < 4; i++)
#pragma unroll
            for (int j = 0; j < 4; j++)
                acc[i][j] = __builtin_amdgcn_mfma_f32_16x16x32_bf16(af[i], bfr[j], acc[i][j], 0, 0, 0);
    }

    // epilogue: bias, ssq (bf16 values), bf16 LDS stash
    float ss[4][4];
#pragma unroll
    for (int i = 0; i < 4; i++)
#pragma unroll
        for (int r = 0; r < 4; r++) ss[i][r] = 0.f;
#pragma unroll
    for (int j = 0; j < 4; j++) {
        const int lcbase = (wave & 1) * 64 + j * 16 + c;
        const float bias = gb[colTile * 128 + lcbase];
#pragma unroll
        for (int i = 0; i < 4; i++) {
#pragma unroll
            for (int r = 0; r < 4; r++) {
                const int lr = (wave >> 1) * 64 + i * 16 + q * 4 + r;
                const float v = acc[i][j][r] + bias;
                const unsigned short hb = bfbits(v);
                Es[lr * EPAD + lcbase] = hb;
                const float vs = bf2f(hb);
                ss[i][r] = fmaf(vs, vs, ss[i][r]);
            }
        }
    }
#pragma unroll
    for (int i = 0; i < 4; i++)
#pragma unroll
        for (int r = 0; r < 4; r++) {
            float s = ss[i][r];
            s += __shfl_xor(s, 1);
            s += __shfl_xor(s, 2);
            s += __shfl_xor(s, 4);
            s += __shfl_xor(s, 8);
            ss[i][r] = s;
        }
    if (c == 0) {
#pragma unroll
        for (int i = 0; i < 4; i++)
#pragma unroll
            for (int r = 0; r < 4; r++) {
                const int rowg = rowTile * 128 + (wave >> 1) * 64 + i * 16 + q * 4 + r;
                atomicAdd(&norm2[rowg], ss[i][r]);
            }
    }
    __syncthreads();

    // fp8 packed store: 8 rbl x 2 ktp x 64 lanes x 16B = 1024 chunks, 4 iters.
    // lane2's 16 bytes = values (r2, k = ktp*64 + {q2*8..+7, 32+q2*8..+7}).
#pragma unroll
    for (int it = 0; it < 4; ++it) {
        const int m = it * 256 + tid;
        const int rbl = m >> 7;             // 0..7
        const int rest = m & 127;
        const int ktpl = rest >> 6;         // 0..1
        const int lane2 = rest & 63;
        const int r2 = lane2 & 15;
        const int q2 = lane2 >> 4;
        const int lr = rbl * 16 + r2;
        const unsigned short* e0 = &Es[lr * EPAD + ktpl * 64 + q2 * 8];
        const unsigned short* e1 = e0 + 32;
        union { unsigned char b[16]; uint4 v; } outw;
#pragma unroll
        for (int t = 0; t < 8; t++) outw.b[t]     = f8bits(bf2f(e0[t]));
#pragma unroll
        for (int t = 0; t < 8; t++) outw.b[8 + t] = f8bits(bf2f(e1[t]));
        const size_t rb = (size_t)(rowTile * 8 + rbl);
        const size_t ktp = (size_t)(colTile * 2 + ktpl);
        *(uint4*)(embpk8 + ((rb * NKTP_E + ktp) * 64 + lane2) * 16) = outw.v;
    }
}

// ---------------------------------------------------------------------------
// Finalize: norm2[i] -> inv_norm^3 (X rows), inv_norm^3 * (2r-1) (D rows)
// ---------------------------------------------------------------------------
__global__ void finalize_kernel(float* __restrict__ nf, const float* __restrict__ r)
{
    const int i = blockIdx.x * 256 + threadIdx.x;
    if (i >= P_B + P_N) return;
    float nrm = sqrtf(nf[i]);
    nrm = fmaxf(nrm, 1e-12f);
    const float inv = 1.0f / nrm;
    float w = inv * inv * inv;
    if (i >= P_B) {
        const float rv = r[i - P_B];
        w *= (2.0f * rv - 1.0f);
    }
    nf[i] = w;
}

// ---------------------------------------------------------------------------
// Echo (fp8): r6-proven supertile mapping + barrier-free fragment K-loop on
// fp8 e4m3 operands. One dwordx4 per fragment-pair (K=64); two
// mfma_f32_16x16x32_fp8_fp8 per pair. Bytes halved, load instrs quartered
// vs bf16; MFMA count identical (fp8 = bf16 rate).
// ---------------------------------------------------------------------------
__global__ __launch_bounds__(256, 2) void echo_pk_kernel(
    const unsigned char* __restrict__ embpk8, const float* __restrict__ fbuf,
    float* __restrict__ echo)
{
    const int tid = threadIdx.x, lane = tid & 63, wave = tid >> 6;
    const int q = lane >> 4, c = lane & 15;
    const int bid = blockIdx.x;          // 0..4095
    const int sb = bid >> 6, w = bid & 63;
    const int btile = (sb & 3) * 8 + (w & 7);    // 0..31
    const int ntile = (sb >> 2) * 8 + (w >> 3);  // 0..127
    const int row0 = btile * 128;
    const int col0 = ntile * 128;
    const int rbA0 = btile * 8 + (wave >> 1) * 4;
    const int rbB0 = 256 + ntile * 8 + (wave & 1) * 4;   // De rows start at rb 256

    const unsigned char* pa[4];
    const unsigned char* pb[4];
#pragma unroll
    for (int i = 0; i < 4; i++)
        pa[i] = embpk8 + ((size_t)(rbA0 + i) * NKTP_E * 64 + lane) * 16;
#pragma unroll
    for (int j = 0; j < 4; j++)
        pb[j] = embpk8 + ((size_t)(rbB0 + j) * NKTP_E * 64 + lane) * 16;

    f32x4 acc[4][4];
    const f32x4 zero = {0.f, 0.f, 0.f, 0.f};
#pragma unroll
    for (int i = 0; i < 4; i++)
#pragma unroll
        for (int j = 0; j < 4; j++) acc[i][j] = zero;

#pragma unroll
    for (int ktp = 0; ktp < NKTP_E; ++ktp) {
        union { uint4 v; long l[2]; } ua[4], ub[4];
#pragma unroll
        for (int i = 0; i < 4; i++) ua[i].v = *(const uint4*)(pa[i] + (size_t)ktp * 1024);
#pragma unroll
        for (int j = 0; j < 4; j++) ub[j].v = *(const uint4*)(pb[j] + (size_t)ktp * 1024);
#pragma unroll
        for (int h = 0; h < 2; h++)
#pragma unroll
            for (int i = 0; i < 4; i++)
#pragma unroll
                for (int j = 0; j < 4; j++)
                    acc[i][j] = __builtin_amdgcn_mfma_f32_16x16x32_fp8_fp8(
                        ua[i].l[h], ub[j].l[h], acc[i][j], 0, 0, 0);
    }

    // epilogue: cube, weight by (ind^3*r2), reduce over columns, atomicAdd rows
    const float* fX = fbuf;
    const float* fD = fbuf + P_B;
    float wc[4];
#pragma unroll
    for (int j = 0; j < 4; j++) wc[j] = fD[col0 + (wave & 1) * 64 + j * 16 + c];
    float p[4][4];
#pragma unroll
    for (int i = 0; i < 4; i++)
#pragma unroll
        for (int r = 0; r < 4; r++) p[i][r] = 0.f;
#pragma unroll
    for (int i = 0; i < 4; i++)
#pragma unroll
        for (int j = 0; j < 4; j++)
#pragma unroll
            for (int r = 0; r < 4; r++) {
                const float v = acc[i][j][r];
                const float v3 = v * v * v;
                p[i][r] = fmaf(v3, wc[j], p[i][r]);
            }
#pragma unroll
    for (int i = 0; i < 4; i++)
#pragma unroll
        for (int r = 0; r < 4; r++) {
            float s = p[i][r];
            s += __shfl_xor(s, 1);
            s += __shfl_xor(s, 2);
            s += __shfl_xor(s, 4);
            s += __shfl_xor(s, 8);
            p[i][r] = s;
        }
    if (c == 0) {
#pragma unroll
        for (int i = 0; i < 4; i++)
#pragma unroll
            for (int r = 0; r < 4; r++) {
                const int rowg = row0 + (wave >> 1) * 64 + i * 16 + q * 4 + r;
                atomicAdd(&echo[rowg], p[i][r] * fX[rowg]);
            }
    }
}

// ---------------------------------------------------------------------------
// Head: logits = echo*h_w + h_b ; preds = sigmoid(logits)
// ---------------------------------------------------------------------------
__global__ void head_kernel(const float* __restrict__ echo, const float* __restrict__ hw,
                            const float* __restrict__ hb, float* __restrict__ out)
{
    const int i = blockIdx.x * 256 + threadIdx.x;
    if (i >= P_B) return;
    const float logit = fmaf(echo[i], hw[0], hb[0]);
    out[i] = logit;
    out[P_B + i] = 1.0f / (1.0f + expf(-logit));
}

extern "C" void kernel_launch(void* const* d_in, const int* in_sizes, int n_in,
                              void* d_out, int out_size, void* d_ws, size_t ws_size,
                              hipStream_t stream)
{
    const float* X  = (const float*)d_in[0];
    const float* D  = (const float*)d_in[1];
    const float* r  = (const float*)d_in[2];
    const float* gw = (const float*)d_in[3];
    const float* gb = (const float*)d_in[4];
    const float* hw = (const float*)d_in[5];
    const float* hb = (const float*)d_in[6];
    float* out = (float*)d_out;

    char* ws = (char*)d_ws;
    const size_t xdpk_bytes   = (size_t)1280 * NKT_F * 64 * 8 * 2;    // 31,457,280
    const size_t gwpk_bytes   = (size_t)32 * NKT_F * 64 * 8 * 2;      //    786,432
    const size_t embpk8_bytes = (size_t)1280 * NKTP_E * 64 * 16;      // 10,485,760

    unsigned short* xdpk   = (unsigned short*)ws;
    unsigned short* gwpk   = (unsigned short*)(ws + xdpk_bytes);
    unsigned char*  embpk8 = (unsigned char*)(ws + xdpk_bytes + gwpk_bytes);
    float* norm2 = (float*)(ws + xdpk_bytes + gwpk_bytes + embpk8_bytes);
    float* echo = norm2 + (P_B + P_N);

    convert_pack_kernel<<<dim3(1312), 256, 0, stream>>>(X, D, gw, xdpk, gwpk, norm2);
    embed_pk_kernel<<<dim3(4, 160), 256, 0, stream>>>(xdpk, gwpk, gb, embpk8, norm2);
    finalize_kernel<<<dim3((P_B + P_N + 255) / 256), 256, 0, stream>>>(norm2, r);
    echo_pk_kernel<<<dim3(4096), 256, 0, stream>>>(embpk8, norm2, echo);
    head_kernel<<<dim3((P_B + 255) / 256), 256, 0, stream>>>(echo, hw, hb, out);
}